// Round 1
// baseline (105.637 us; speedup 1.0000x reference)
//
#include <hip/hip_runtime.h>

// extract_patches: in [B=16, W=112, H=112, D=128] f32
// K0=K1=4, S0=S1=2 -> nh=nv=55
// out[b][ph*55+pv][(k0*4+k1)*128 + d] = in[b][ph*2+k0][pv*2+k1][d]
// out: [16, 3025, 2048] f32
//
// One block per output patch (b,ph,pv): 512 threads, each moves one float4.
// tid = k0*128 + k1*32 + d4  ==  output float4 offset within the patch.

#define NH 55
#define NV 55
#define W_IN 112
#define H_IN 112
#define D4 32   // 128 floats / 4

__global__ __launch_bounds__(512) void patch_copy_kernel(
    const float* __restrict__ in, float* __restrict__ out) {
    const int blk = blockIdx.x;                 // b*3025 + ph*55 + pv
    const int pv = blk % NV;
    const int t1 = blk / NV;
    const int ph = t1 % NH;
    const int b  = t1 / NH;

    const int tid = threadIdx.x;                // 0..511
    const int d4 = tid & 31;
    const int k1 = (tid >> 5) & 3;
    const int k0 = tid >> 7;

    const int w = ph * 2 + k0;                  // <= 108+3 = 111 < 112
    const int h = pv * 2 + k1;

    const float4* __restrict__ src =
        reinterpret_cast<const float4*>(in) +
        ((size_t)((b * W_IN + w) * H_IN + h) * D4 + d4);
    float4* __restrict__ dst =
        reinterpret_cast<float4*>(out) + ((size_t)blk * 512 + tid);

    *dst = *src;
}

extern "C" void kernel_launch(void* const* d_in, const int* in_sizes, int n_in,
                              void* d_out, int out_size, void* d_ws, size_t ws_size,
                              hipStream_t stream) {
    const float* in = (const float*)d_in[0];
    float* out = (float*)d_out;

    const int nblocks = 16 * NH * NV;           // 48400
    patch_copy_kernel<<<nblocks, 512, 0, stream>>>(in, out);
}

// Round 3
// 94.344 us; speedup vs baseline: 1.1197x; 1.1197x over previous
//
#include <hip/hip_runtime.h>

// extract_patches: in [B=16, W=112, H=112, D=128] f32
// K0=K1=4, S0=S1=2 -> nh=nv=55
// out[b][ph*55+pv][(k0*4+k1)*128 + d] = in[b][ph*2+k0][pv*2+k1][d]
// out: [16, 3025, 2048] f32
//
// R3: 8 patches per block (512 threads). Each thread does 8 independent
// float4 copies: all loads issued first (8 VMEM in flight per wave), then
// 8 nontemporal stores (write stream bypasses cache so the 103 MB input
// stays L3-resident for the 4x patch-overlap reuse).
// Uses clang ext_vector float4 (nontemporal builtin rejects HIP_vector_type).
// tid = k0*128 + k1*32 + d4 == output float4 offset within the patch.

typedef float f32x4 __attribute__((ext_vector_type(4)));

#define NH 55
#define NV 55
#define W_IN 112
#define H_IN 112
#define D4 32            // 128 floats / 4
#define PPB 8            // patches per block; 48400 = 8 * 6050

__global__ __launch_bounds__(512) void patch_copy_kernel(
    const float* __restrict__ in, float* __restrict__ out) {
    const int base = blockIdx.x * PPB;          // first patch of this block

    const int tid = threadIdx.x;                // 0..511
    const int d4 = tid & 31;
    const int k1 = (tid >> 5) & 3;
    const int k0 = tid >> 7;

    const f32x4* __restrict__ src4 = reinterpret_cast<const f32x4*>(in);
    f32x4* __restrict__ dst4 = reinterpret_cast<f32x4*>(out);

    f32x4 v[PPB];

    #pragma unroll
    for (int p = 0; p < PPB; ++p) {
        const int blk = base + p;               // b*3025 + ph*55 + pv
        const int pv = blk % NV;
        const int t1 = blk / NV;
        const int ph = t1 % NH;
        const int b  = t1 / NH;
        const int w = ph * 2 + k0;              // <= 111
        const int h = pv * 2 + k1;
        v[p] = src4[(size_t)((b * W_IN + w) * H_IN + h) * D4 + d4];
    }

    #pragma unroll
    for (int p = 0; p < PPB; ++p) {
        const int blk = base + p;
        __builtin_nontemporal_store(v[p], &dst4[(size_t)blk * 512 + tid]);
    }
}

extern "C" void kernel_launch(void* const* d_in, const int* in_sizes, int n_in,
                              void* d_out, int out_size, void* d_ws, size_t ws_size,
                              hipStream_t stream) {
    const float* in = (const float*)d_in[0];
    float* out = (float*)d_out;

    const int nblocks = 16 * NH * NV / PPB;     // 6050
    patch_copy_kernel<<<nblocks, 512, 0, stream>>>(in, out);
}

// Round 4
// 88.242 us; speedup vs baseline: 1.1971x; 1.0692x over previous
//
#include <hip/hip_runtime.h>

// extract_patches: in [B=16, W=112, H=112, D=128] f32
// K0=K1=4, S0=S1=2 -> nh=nv=55
// out[b][ph*55+pv][(k0*4+k1)*128 + d] = in[b][ph*2+k0][pv*2+k1][d]
// out: [16, 3025, 2048] f32
//
// R4: INVERTED (scatter) formulation. Iterate over input: each float4 is
// loaded exactly ONCE from HBM (103 MB guaranteed read traffic, no cache
// reliance) and nontemporal-stored to its <=4 output positions
// (k0 = w-2ph in {w&1, (w&1)+2}; k1 likewise from h). The patch->pixel map
// is a bijection, so every output element is written exactly once.
// One block per input row (b,w): 512 threads x 7 iters cover 112 h x 32 d4.
// All 7 loads issued up front (7-deep MLP). ph-validity is wave-uniform.

typedef float f32x4 __attribute__((ext_vector_type(4)));

#define W_IN 112
#define H_IN 112
#define NH 55
#define NV 55
#define D4 32     // 128 floats / 4
#define ITERS 7   // 112 h / 16 h-per-iter

__global__ __launch_bounds__(512) void scatter_kernel(
    const float* __restrict__ in, float* __restrict__ out) {
    const int blk = blockIdx.x;            // b*112 + w
    const int w = blk % W_IN;
    const int b = blk / W_IN;
    const int tid = threadIdx.x;
    const int d4 = tid & 31;
    const int dh = tid >> 5;               // 0..15

    // k0 candidates for this row (wave-uniform): k0 == w (mod 2)
    const int k0a = w & 1;
    const int pha = (w - k0a) >> 1;        // == 55 (invalid) when w >= 110
    const int k0b = k0a + 2;
    const int phb = pha - 1;               // == -1 (invalid) when w <= 1
    const bool vA = (pha < NH);
    const bool vB = (phb >= 0);
    const int pha_c = vA ? pha : 0;        // clamp for safe address calc
    const int phb_c = vB ? phb : 0;

    const f32x4* __restrict__ src4 = reinterpret_cast<const f32x4*>(in);
    f32x4* __restrict__ dst4 = reinterpret_cast<f32x4*>(out);

    f32x4 v[ITERS];
    #pragma unroll
    for (int it = 0; it < ITERS; ++it) {
        const int h = it * 16 + dh;
        v[it] = src4[(size_t)(blk * H_IN + h) * D4 + d4];
    }

    // patch float4 size = 16*128/4 = 512; out idx = patch*512 + (k0*4+k1)*32 + d4
    const size_t baseA = (size_t)(b * (NH * NV) + pha_c * NV) * 512 + (size_t)(k0a * 128) + d4;
    const size_t baseB = (size_t)(b * (NH * NV) + phb_c * NV) * 512 + (size_t)(k0b * 128) + d4;

    #pragma unroll
    for (int it = 0; it < ITERS; ++it) {
        const int h = it * 16 + dh;
        const int k1a = h & 1;
        const int pva = (h - k1a) >> 1;    // == 55 (invalid) when h >= 110
        const int pvb = pva - 1;           // == -1 (invalid) when h <= 1
        const int k1b = k1a + 2;
        const bool vC = (pva < NV);
        const bool vD = (pvb >= 0);
        const size_t offC = (size_t)(vC ? pva : 0) * 512 + (size_t)(k1a * 32);
        const size_t offD = (size_t)(vD ? pvb : 0) * 512 + (size_t)(k1b * 32);
        if (vA) {
            if (vC) __builtin_nontemporal_store(v[it], &dst4[baseA + offC]);
            if (vD) __builtin_nontemporal_store(v[it], &dst4[baseA + offD]);
        }
        if (vB) {
            if (vC) __builtin_nontemporal_store(v[it], &dst4[baseB + offC]);
            if (vD) __builtin_nontemporal_store(v[it], &dst4[baseB + offD]);
        }
    }
}

extern "C" void kernel_launch(void* const* d_in, const int* in_sizes, int n_in,
                              void* d_out, int out_size, void* d_ws, size_t ws_size,
                              hipStream_t stream) {
    const float* in = (const float*)d_in[0];
    float* out = (float*)d_out;

    const int nblocks = 16 * W_IN;          // 1792 blocks, one per input row
    scatter_kernel<<<nblocks, 512, 0, stream>>>(in, out);
}